// Round 10
// baseline (194.905 us; speedup 1.0000x reference)
//
#include <hip/hip_runtime.h>

#define N_NODES 100000
#define N_EDGES 1600000
#define IN_DIM 128
#define OUT_DIM 32

typedef _Float16 h2 __attribute__((ext_vector_type(2)));
typedef _Float16 h4 __attribute__((ext_vector_type(4)));

#define FMA4(acc, s, wv)                  \
  acc.x = fmaf(s, wv.x, acc.x);           \
  acc.y = fmaf(s, wv.y, acc.y);           \
  acc.z = fmaf(s, wv.z, acc.z);           \
  acc.w = fmaf(s, wv.w, acc.w)

// -------- kernel 1: support(fp16) = X @ W, register-blocked (proven R9) ----
__global__ __launch_bounds__(256) void gemm_support(
    const float* __restrict__ x, const float* __restrict__ w,
    _Float16* __restrict__ support, uint4* __restrict__ out_h_vec) {
  __shared__ float xs[64][132];        // 33,792 B (pad 132: 2-way max)
  __shared__ float w4[8][129][4];      // 16,512 B (pad 129: perfect spread)
  const int t = threadIdx.x;
  const long long row0 = (long long)blockIdx.x * 64;

  for (int i = t; i < IN_DIM * OUT_DIM; i += 256) {
    const int k = i >> 5, c = i & 31;
    w4[c >> 2][k][c & 3] = w[i];
  }
  for (int j = t; j < 64 * (IN_DIM / 4); j += 256) {
    const int r = j >> 5;
    const int f = j & 31;
    const long long row = row0 + r;
    float4 v = (row < N_NODES) ? ((const float4*)x)[row * (IN_DIM / 4) + f]
                               : make_float4(0.f, 0.f, 0.f, 0.f);
    *(float4*)&xs[r][f * 4] = v;
  }
  __syncthreads();

  const int rr = t >> 3;   // 0..31
  const int cc = t & 7;    // 0..7
  float4 a0 = make_float4(0.f, 0.f, 0.f, 0.f);
  float4 a1 = make_float4(0.f, 0.f, 0.f, 0.f);
#pragma unroll
  for (int k4 = 0; k4 < IN_DIM / 4; ++k4) {
    const int k = k4 * 4;
    const float4 xv0 = *(const float4*)&xs[2 * rr][k];
    const float4 xv1 = *(const float4*)&xs[2 * rr + 1][k];
    const float4 w0 = *(const float4*)&w4[cc][k][0];
    const float4 w1 = *(const float4*)&w4[cc][k + 1][0];
    const float4 w2 = *(const float4*)&w4[cc][k + 2][0];
    const float4 w3 = *(const float4*)&w4[cc][k + 3][0];
    FMA4(a0, xv0.x, w0); FMA4(a0, xv0.y, w1);
    FMA4(a0, xv0.z, w2); FMA4(a0, xv0.w, w3);
    FMA4(a1, xv1.x, w0); FMA4(a1, xv1.y, w1);
    FMA4(a1, xv1.z, w2); FMA4(a1, xv1.w, w3);
  }

  const long long r0 = row0 + 2 * rr;
  if (r0 < N_NODES) {
    h4 o = { (_Float16)a0.x, (_Float16)a0.y, (_Float16)a0.z, (_Float16)a0.w };
    *(h4*)(support + r0 * OUT_DIM + 4 * cc) = o;
  }
  const long long r1 = r0 + 1;
  if (r1 < N_NODES) {
    h4 o = { (_Float16)a1.x, (_Float16)a1.y, (_Float16)a1.z, (_Float16)a1.w };
    *(h4*)(support + r1 * OUT_DIM + 4 * cc) = o;
  }

  const int g = blockIdx.x * 256 + t;
  if (g < N_NODES * OUT_DIM * 2 / 16) out_h_vec[g] = make_uint4(0, 0, 0, 0);
}

// -------- packed v2f16 atomic add (HW fadd; CAS fallback) --------
__device__ __forceinline__ void pk_atomic_add_h2(h2* p, h2 v) {
#if __has_builtin(__builtin_amdgcn_global_atomic_fadd_v2f16)
  __builtin_amdgcn_global_atomic_fadd_v2f16(
      (__attribute__((address_space(1))) h2*)p, v);
#else
  unsigned* pu = (unsigned*)p;
  unsigned old = *pu;
  while (true) {
    h2 cur = __builtin_bit_cast(h2, old);
    h2 nv = cur + v;
    unsigned n = __builtin_bit_cast(unsigned, nv);
    unsigned r = atomicCAS(pu, old, n);
    if (r == old) break;
    old = r;
  }
#endif
}

// -------- kernel 2: scatter, 8 lanes/edge, 2 pk-f16 atomics per thread -----
// Same 25.6M atomic ops, half the index reads and address setup per op.
// Grid exactly N_EDGES*8/256 = 50,000 blocks; no guard needed.
__global__ __launch_bounds__(256) void scatter_h2x2(
    const int* __restrict__ rows, const int* __restrict__ cols,
    const float* __restrict__ vals, const _Float16* __restrict__ support,
    h2* __restrict__ out_h) {
  const long long gid = (long long)blockIdx.x * 256 + threadIdx.x;
  const int e = (int)(gid >> 3);
  const int l = (int)(gid & 7);           // 0..7: pairs l and l+8
  const int r = rows[e];
  const int c = cols[e];
  const float v = vals[e];
  const _Float16* srow = support + (long long)c * OUT_DIM;
  const h2 s0 = *(const h2*)(srow + 2 * l);        // dims 2l,2l+1
  const h2 s1 = *(const h2*)(srow + 2 * l + 16);   // dims 2l+16,2l+17
  h2 i0 = { (_Float16)(v * (float)s0[0]), (_Float16)(v * (float)s0[1]) };
  h2 i1 = { (_Float16)(v * (float)s1[0]), (_Float16)(v * (float)s1[1]) };
  h2* orow = out_h + (long long)r * 16;
  pk_atomic_add_h2(orow + l, i0);
  pk_atomic_add_h2(orow + l + 8, i1);
}

// -------- kernel 3: finalize out = fp32(out_h) + bias ----------------------
__global__ __launch_bounds__(256) void finalize_h(
    const h2* __restrict__ out_h, const float* __restrict__ bias,
    float* __restrict__ out) {
  const int i = blockIdx.x * 256 + threadIdx.x;     // 8-elem group index
  if (i >= N_NODES * OUT_DIM / 8) return;
  const h2* src = out_h + i * 4;
  float4 a, b;
  h2 p0 = src[0], p1 = src[1], p2 = src[2], p3 = src[3];
  const int d0 = (i * 8) & 31;
  a.x = (float)p0[0] + bias[d0 + 0];
  a.y = (float)p0[1] + bias[d0 + 1];
  a.z = (float)p1[0] + bias[d0 + 2];
  a.w = (float)p1[1] + bias[d0 + 3];
  b.x = (float)p2[0] + bias[d0 + 4];
  b.y = (float)p2[1] + bias[d0 + 5];
  b.z = (float)p3[0] + bias[d0 + 6];
  b.w = (float)p3[1] + bias[d0 + 7];
  float4* dst = (float4*)(out + (long long)i * 8);
  dst[0] = a;
  dst[1] = b;
}

extern "C" void kernel_launch(void* const* d_in, const int* in_sizes, int n_in,
                              void* d_out, int out_size, void* d_ws, size_t ws_size,
                              hipStream_t stream) {
  const float* x        = (const float*)d_in[0];
  const int*   adj_rows = (const int*)d_in[1];
  const int*   adj_cols = (const int*)d_in[2];
  const float* adj_vals = (const float*)d_in[3];
  const float* weight   = (const float*)d_in[4];
  const float* bias     = (const float*)d_in[5];
  float* out = (float*)d_out;

  // ---- workspace: support fp16 (6.4 MB) + out_h fp16 (6.4 MB) ----
  char* wsp = (char*)d_ws;
  _Float16* support = (_Float16*)wsp;               // 6,400,000 B
  h2* out_h = (h2*)(wsp + 6400000);                 // 6,400,000 B

  gemm_support<<<(N_NODES + 63) / 64, 256, 0, stream>>>(
      x, weight, support, (uint4*)out_h);
  {
    const long long total = (long long)N_EDGES * 8;
    scatter_h2x2<<<(int)(total / 256), 256, 0, stream>>>(
        adj_rows, adj_cols, adj_vals, support, out_h);
  }
  {
    const int total = N_NODES * OUT_DIM / 8;
    finalize_h<<<(total + 255) / 256, 256, 0, stream>>>(out_h, bias, out);
  }
}

// Round 11
// 118.840 us; speedup vs baseline: 1.6401x; 1.6401x over previous
//
#include <hip/hip_runtime.h>

#define N_NODES 100000
#define N_EDGES 1600000
#define IN_DIM 128
#define OUT_DIM 32

typedef _Float16 h2 __attribute__((ext_vector_type(2)));
typedef _Float16 h4 __attribute__((ext_vector_type(4)));

#define FMA4(acc, s, wv)                  \
  acc.x = fmaf(s, wv.x, acc.x);           \
  acc.y = fmaf(s, wv.y, acc.y);           \
  acc.z = fmaf(s, wv.z, acc.z);           \
  acc.w = fmaf(s, wv.w, acc.w)

// -------- kernel 1: support(fp16) = X @ W, register-blocked (proven R9) ----
__global__ __launch_bounds__(256) void gemm_support(
    const float* __restrict__ x, const float* __restrict__ w,
    _Float16* __restrict__ support, uint4* __restrict__ out_h_vec) {
  __shared__ float xs[64][132];        // 33,792 B (pad 132: 2-way max)
  __shared__ float w4[8][129][4];      // 16,512 B (pad 129: perfect spread)
  const int t = threadIdx.x;
  const long long row0 = (long long)blockIdx.x * 64;

  for (int i = t; i < IN_DIM * OUT_DIM; i += 256) {
    const int k = i >> 5, c = i & 31;
    w4[c >> 2][k][c & 3] = w[i];
  }
  for (int j = t; j < 64 * (IN_DIM / 4); j += 256) {
    const int r = j >> 5;
    const int f = j & 31;
    const long long row = row0 + r;
    float4 v = (row < N_NODES) ? ((const float4*)x)[row * (IN_DIM / 4) + f]
                               : make_float4(0.f, 0.f, 0.f, 0.f);
    *(float4*)&xs[r][f * 4] = v;
  }
  __syncthreads();

  const int rr = t >> 3;   // 0..31
  const int cc = t & 7;    // 0..7
  float4 a0 = make_float4(0.f, 0.f, 0.f, 0.f);
  float4 a1 = make_float4(0.f, 0.f, 0.f, 0.f);
#pragma unroll
  for (int k4 = 0; k4 < IN_DIM / 4; ++k4) {
    const int k = k4 * 4;
    const float4 xv0 = *(const float4*)&xs[2 * rr][k];
    const float4 xv1 = *(const float4*)&xs[2 * rr + 1][k];
    const float4 w0 = *(const float4*)&w4[cc][k][0];
    const float4 w1 = *(const float4*)&w4[cc][k + 1][0];
    const float4 w2 = *(const float4*)&w4[cc][k + 2][0];
    const float4 w3 = *(const float4*)&w4[cc][k + 3][0];
    FMA4(a0, xv0.x, w0); FMA4(a0, xv0.y, w1);
    FMA4(a0, xv0.z, w2); FMA4(a0, xv0.w, w3);
    FMA4(a1, xv1.x, w0); FMA4(a1, xv1.y, w1);
    FMA4(a1, xv1.z, w2); FMA4(a1, xv1.w, w3);
  }

  const long long r0 = row0 + 2 * rr;
  if (r0 < N_NODES) {
    h4 o = { (_Float16)a0.x, (_Float16)a0.y, (_Float16)a0.z, (_Float16)a0.w };
    *(h4*)(support + r0 * OUT_DIM + 4 * cc) = o;
  }
  const long long r1 = r0 + 1;
  if (r1 < N_NODES) {
    h4 o = { (_Float16)a1.x, (_Float16)a1.y, (_Float16)a1.z, (_Float16)a1.w };
    *(h4*)(support + r1 * OUT_DIM + 4 * cc) = o;
  }

  // fused zero of out_h: 400,000 uint4 (6.4 MB), 1563*256 = 400,128 threads
  const int g = blockIdx.x * 256 + t;
  if (g < N_NODES * OUT_DIM * 2 / 16) out_h_vec[g] = make_uint4(0, 0, 0, 0);
}

// -------- packed v2f16 atomic add (HW fadd; CAS fallback) --------
__device__ __forceinline__ void pk_atomic_add_h2(h2* p, h2 v) {
#if __has_builtin(__builtin_amdgcn_global_atomic_fadd_v2f16)
  __builtin_amdgcn_global_atomic_fadd_v2f16(
      (__attribute__((address_space(1))) h2*)p, v);
#else
  unsigned* pu = (unsigned*)p;
  unsigned old = *pu;
  while (true) {
    h2 cur = __builtin_bit_cast(h2, old);
    h2 nv = cur + v;
    unsigned n = __builtin_bit_cast(unsigned, nv);
    unsigned r = atomicCAS(pu, old, n);
    if (r == old) break;
    old = r;
  }
#endif
}

// -------- kernel 2: edge-parallel scatter, pk-f16 atomics (op roofline) ----
// 16 lanes/edge, 1 atomic/thread: each 16-lane group covers one contiguous
// 64B output row (optimal TCC segment geometry — R10 probe confirmed).
// Grid exactly N_EDGES*16/256 = 100,000 blocks; no guard needed.
__global__ __launch_bounds__(256) void scatter_h2(
    const int* __restrict__ rows, const int* __restrict__ cols,
    const float* __restrict__ vals, const _Float16* __restrict__ support,
    h2* __restrict__ out_h) {
  const long long gid = (long long)blockIdx.x * 256 + threadIdx.x;
  const int e = (int)(gid >> 4);
  const int l = (int)(gid & 15);          // dim-pair index 0..15
  const int r = rows[e];
  const int c = cols[e];
  const float v = vals[e];
  const h2 s = *(const h2*)(support + (long long)c * OUT_DIM + 2 * l);
  h2 inc = { (_Float16)(v * (float)s[0]), (_Float16)(v * (float)s[1]) };
  pk_atomic_add_h2(out_h + (long long)r * 16 + l, inc);
}

// -------- kernel 3: finalize out = fp32(out_h) + bias ----------------------
__global__ __launch_bounds__(256) void finalize_h(
    const h2* __restrict__ out_h, const float* __restrict__ bias,
    float* __restrict__ out) {
  const int i = blockIdx.x * 256 + threadIdx.x;     // 8-elem group index
  if (i >= N_NODES * OUT_DIM / 8) return;
  const h2* src = out_h + i * 4;
  float4 a, b;
  h2 p0 = src[0], p1 = src[1], p2 = src[2], p3 = src[3];
  const int d0 = (i * 8) & 31;
  a.x = (float)p0[0] + bias[d0 + 0];
  a.y = (float)p0[1] + bias[d0 + 1];
  a.z = (float)p1[0] + bias[d0 + 2];
  a.w = (float)p1[1] + bias[d0 + 3];
  b.x = (float)p2[0] + bias[d0 + 4];
  b.y = (float)p2[1] + bias[d0 + 5];
  b.z = (float)p3[0] + bias[d0 + 6];
  b.w = (float)p3[1] + bias[d0 + 7];
  float4* dst = (float4*)(out + (long long)i * 8);
  dst[0] = a;
  dst[1] = b;
}

extern "C" void kernel_launch(void* const* d_in, const int* in_sizes, int n_in,
                              void* d_out, int out_size, void* d_ws, size_t ws_size,
                              hipStream_t stream) {
  const float* x        = (const float*)d_in[0];
  const int*   adj_rows = (const int*)d_in[1];
  const int*   adj_cols = (const int*)d_in[2];
  const float* adj_vals = (const float*)d_in[3];
  const float* weight   = (const float*)d_in[4];
  const float* bias     = (const float*)d_in[5];
  float* out = (float*)d_out;

  // ---- workspace: support fp16 (6.4 MB) + out_h fp16 (6.4 MB) ----
  char* wsp = (char*)d_ws;
  _Float16* support = (_Float16*)wsp;               // 6,400,000 B
  h2* out_h = (h2*)(wsp + 6400000);                 // 6,400,000 B

  gemm_support<<<(N_NODES + 63) / 64, 256, 0, stream>>>(
      x, weight, support, (uint4*)out_h);
  {
    const long long total = (long long)N_EDGES * 16;
    scatter_h2<<<(int)(total / 256), 256, 0, stream>>>(
        adj_rows, adj_cols, adj_vals, support, out_h);
  }
  {
    const int total = N_NODES * OUT_DIM / 8;
    finalize_h<<<(total + 255) / 256, 256, 0, stream>>>(out_h, bias, out);
  }
}